// Round 2
// baseline (770.074 us; speedup 1.0000x reference)
//
#include <hip/hip_runtime.h>
#include <hip/hip_bf16.h>

#define G_ 2048
#define NPG_ 128
#define INC_ 151
#define HID_ 64
#define NNODES_ (G_ * NPG_)      // 262144
#define NEDGES_ 2097152

typedef __hip_bfloat16 bf16;

static __device__ __forceinline__ __hip_bfloat162 f2bf2(float a, float b) {
    __hip_bfloat162 r;
    r.x = __float2bfloat16(a);
    r.y = __float2bfloat16(b);
    return r;
}

// ---------------------------------------------------------------------------
// K1: h = x @ W1 (bf16 out), as_[n] = h[n].att_src, ad_[n] = h[n].att_dst
// Block = 256 threads = 4 waves; each wave: 8 nodes, lane = output feature f.
// ---------------------------------------------------------------------------
__global__ void __launch_bounds__(256) k1_gemm(
        const float* __restrict__ x, const float* __restrict__ W1,
        const float* __restrict__ att_src, const float* __restrict__ att_dst,
        bf16* __restrict__ h, float* __restrict__ as_, float* __restrict__ ad_) {
    __shared__ __align__(16) float xs[32 * 152];
    __shared__ __align__(16) float ws[152 * 64];
    const int tid = threadIdx.x;
    const int base = blockIdx.x * 32;

    // stage W1 (151*64 = 9664 floats), zero-pad rows >=151
    const float4* W4 = (const float4*)W1;
    for (int i4 = tid; i4 < 2432; i4 += 256) {
        float4 v = (i4 < 2416) ? W4[i4] : make_float4(0.f, 0.f, 0.f, 0.f);
        ((float4*)ws)[i4] = v;
    }
    // stage x rows, pad 151 -> 152 with zeros
    for (int idx = tid; idx < 32 * 152; idx += 256) {
        int row = idx / 152;
        int k = idx - row * 152;
        xs[idx] = (k < 151) ? x[(size_t)(base + row) * 151 + k] : 0.f;
    }
    __syncthreads();

    const int wv = tid >> 6, lane = tid & 63;
    float acc[8];
#pragma unroll
    for (int m = 0; m < 8; m++) acc[m] = 0.f;

    for (int k = 0; k < 152; k += 4) {
        float w0 = ws[(k + 0) * 64 + lane];
        float w1 = ws[(k + 1) * 64 + lane];
        float w2 = ws[(k + 2) * 64 + lane];
        float w3 = ws[(k + 3) * 64 + lane];
#pragma unroll
        for (int m = 0; m < 8; m++) {
            float4 xv = *(const float4*)&xs[(wv * 8 + m) * 152 + k];
            acc[m] += xv.x * w0 + xv.y * w1 + xv.z * w2 + xv.w * w3;
        }
    }

    float asf = att_src[lane], adf = att_dst[lane];
#pragma unroll
    for (int m = 0; m < 8; m++) {
        int node = base + wv * 8 + m;
        h[(size_t)node * 64 + lane] = __float2bfloat16(acc[m]);
        float s = acc[m] * asf;
        float d = acc[m] * adf;
#pragma unroll
        for (int off = 32; off; off >>= 1) {
            s += __shfl_xor(s, off);
            d += __shfl_xor(d, off);
        }
        if (lane == 0) { as_[node] = s; ad_[node] = d; }
    }
}

// ---------------------------------------------------------------------------
// K2: per-edge: ex = exp(leakyrelu(as[src] + ad[dst])); AT[g][src_l][dst_l] += ex
// ---------------------------------------------------------------------------
__global__ void __launch_bounds__(256) k2_edges(
        const int* __restrict__ ei, const float* __restrict__ as_,
        const float* __restrict__ ad_, float* __restrict__ AT) {
    int e = blockIdx.x * 256 + threadIdx.x;
    if (e >= NEDGES_) return;
    int s = ei[e];
    int d = ei[NEDGES_ + e];
    float a = as_[s] + ad_[d];
    a = (a > 0.f) ? a : 0.2f * a;
    float ex = __expf(a);
    int g = s >> 7;
    atomicAdd(&AT[((size_t)g << 14) + ((size_t)(s & 127) << 7) + (d & 127)], ex);
}

// ---------------------------------------------------------------------------
// K3: one graph per block. See round-0 notes.
// ---------------------------------------------------------------------------
__global__ void __launch_bounds__(256) k3_graph(
        const float* __restrict__ ATg, const bf16* __restrict__ h,
        const float* __restrict__ as_, const float* __restrict__ ad_,
        const float* __restrict__ b1, const float* __restrict__ Wlin,
        const float* __restrict__ blin, float* __restrict__ out) {
    __shared__ __align__(16) bf16 At[128 * 128];
    __shared__ __align__(16) float hs[128 * 64];
    const int tid = threadIdx.x;
    const int g = blockIdx.x;
    const float* Ag = ATg + ((size_t)g << 14);
    const bf16* hg = h + ((size_t)g << 13);

    // 1. stage AT -> bf16 LDS
    for (int i4 = tid; i4 < 4096; i4 += 256) {
        float4 v = ((const float4*)Ag)[i4];
        __hip_bfloat162* d2 = (__hip_bfloat162*)(At + i4 * 4);
        d2[0] = f2bf2(v.x, v.y);
        d2[1] = f2bf2(v.z, v.w);
    }
    __syncthreads();

    // 2. self loops
    if (tid < 128) {
        int node = (g << 7) + tid;
        float a = as_[node] + ad_[node];
        a = (a > 0.f) ? a : 0.2f * a;
        float ex = __expf(a);
        At[tid * 128 + tid] =
            __float2bfloat16(__bfloat162float(At[tid * 128 + tid]) + ex);
    }
    __syncthreads();

    // 3. column sums (denominators) -> normalize columns in place
    const int ic = tid & 127, jh = tid >> 7;
    {
        float p = 0.f;
        for (int j = jh * 64; j < jh * 64 + 64; j++)
            p += __bfloat162float(At[j * 128 + ic]);
        hs[tid] = p;     // scratch (h not staged yet)
    }
    __syncthreads();
    {
        float inv = 1.f / (hs[ic] + hs[ic + 128]);
        for (int j = jh * 64; j < jh * 64 + 64; j++) {
            int ai = j * 128 + ic;
            At[ai] = __float2bfloat16(__bfloat162float(At[ai]) * inv);
        }
    }
    __syncthreads();

    // 4. stage h -> fp32 LDS
    for (int idx = tid; idx < 4096; idx += 256) {
        __hip_bfloat162 hv = ((const __hip_bfloat162*)hg)[idx];
        float2 f2 = __bfloat1622float2(hv);
        *(float2*)&hs[idx * 2] = f2;
    }
    __syncthreads();

    // 5. matmul: wave wv -> rows i = (wv&1)*64 + lane, feats f0 = (wv>>1)*32
    const int wv = tid >> 6, lane = tid & 63;
    const int i = ((wv & 1) << 6) | lane;
    const int f0 = (wv >> 1) << 5;
    float acc[32];
#pragma unroll
    for (int q = 0; q < 32; q++) acc[q] = 0.f;

    for (int j = 0; j < 128; j++) {
        float a = __bfloat162float(At[j * 128 + i]);
        const float4* hp = (const float4*)&hs[(j << 6) + f0];
#pragma unroll
        for (int q = 0; q < 8; q++) {
            float4 hv = hp[q];
            acc[4 * q + 0] += a * hv.x;
            acc[4 * q + 1] += a * hv.y;
            acc[4 * q + 2] += a * hv.z;
            acc[4 * q + 3] += a * hv.w;
        }
    }

    // 6. epilogue: relu(acc + b1) . Wlin
    float p = 0.f;
    const float* wl = Wlin + i * 64 + f0;
#pragma unroll
    for (int q = 0; q < 8; q++) {
        float4 b4 = *(const float4*)&b1[f0 + 4 * q];
        float4 w4 = *(const float4*)&wl[4 * q];
        float o0 = acc[4 * q + 0] + b4.x; o0 = o0 > 0.f ? o0 : 0.f;
        float o1 = acc[4 * q + 1] + b4.y; o1 = o1 > 0.f ? o1 : 0.f;
        float o2 = acc[4 * q + 2] + b4.z; o2 = o2 > 0.f ? o2 : 0.f;
        float o3 = acc[4 * q + 3] + b4.w; o3 = o3 > 0.f ? o3 : 0.f;
        p += o0 * w4.x + o1 * w4.y + o2 * w4.z + o3 * w4.w;
    }
#pragma unroll
    for (int off = 32; off; off >>= 1) p += __shfl_xor(p, off);

    __syncthreads();                 // all waves done reading At -> reuse as scratch
    if (lane == 0) ((float*)At)[wv] = p;
    __syncthreads();
    if (tid == 0) {
        float logit = ((float*)At)[0] + ((float*)At)[1] + ((float*)At)[2] +
                      ((float*)At)[3] + blin[0];
        out[g] = 1.f / (1.f + __expf(-logit));
    }
}

// ---------------------------------------------------------------------------
extern "C" void kernel_launch(void* const* d_in, const int* in_sizes, int n_in,
                              void* d_out, int out_size, void* d_ws, size_t ws_size,
                              hipStream_t stream) {
    (void)in_sizes; (void)n_in; (void)out_size; (void)ws_size;
    const float* x       = (const float*)d_in[0];
    const int*   ei      = (const int*)d_in[1];
    const float* W1      = (const float*)d_in[2];
    const float* att_src = (const float*)d_in[3];
    const float* att_dst = (const float*)d_in[4];
    const float* b1      = (const float*)d_in[5];
    const float* Wlin    = (const float*)d_in[6];
    const float* blin    = (const float*)d_in[7];
    float* out = (float*)d_out;

    char* ws = (char*)d_ws;
    bf16*  h   = (bf16*)ws;                          // 33,554,432 B
    float* as_ = (float*)(ws + 33554432);            // 1 MB
    float* ad_ = (float*)(ws + 34603008);            // 1 MB
    float* AT  = (float*)(ws + 35651584);            // 134,217,728 B

    (void)hipMemsetAsync(AT, 0, (size_t)G_ * NPG_ * NPG_ * sizeof(float), stream);
    k1_gemm<<<NNODES_ / 32, 256, 0, stream>>>(x, W1, att_src, att_dst, h, as_, ad_);
    k2_edges<<<NEDGES_ / 256, 256, 0, stream>>>(ei, as_, ad_, AT);
    k3_graph<<<G_, 256, 0, stream>>>(AT, h, as_, ad_, b1, Wlin, blin, out);
}

// Round 3
// 543.282 us; speedup vs baseline: 1.4174x; 1.4174x over previous
//
#include <hip/hip_runtime.h>
#include <hip/hip_bf16.h>

#define G_ 2048
#define NPG_ 128
#define INC_ 151
#define HID_ 64
#define NNODES_ (G_ * NPG_)      // 262144
#define NEDGES_ 2097152

typedef __hip_bfloat16 bf16;
typedef short bf16x8v __attribute__((ext_vector_type(8)));
typedef float f32x4 __attribute__((ext_vector_type(4)));

static __device__ __forceinline__ __hip_bfloat162 f2bf2(float a, float b) {
    __hip_bfloat162 r;
    r.x = __float2bfloat16(a);
    r.y = __float2bfloat16(b);
    return r;
}
static __device__ __forceinline__ short bfb(float f) {
    __hip_bfloat16 b = __float2bfloat16(f);
    return __builtin_bit_cast(short, b);
}

// ---------------------------------------------------------------------------
// K0: W1 [151][64] fp32 -> Bt [64 n][168 k] bf16 (k>=151 zero-padded)
// ---------------------------------------------------------------------------
__global__ void __launch_bounds__(256) k0_prep(const float* __restrict__ W1,
                                              bf16* __restrict__ Bt) {
    int i = blockIdx.x * 256 + threadIdx.x;
    if (i >= 64 * 168) return;
    int n = i / 168, k = i - n * 168;
    float v = (k < 151) ? W1[k * 64 + n] : 0.f;
    Bt[i] = __float2bfloat16(v);
}

// ---------------------------------------------------------------------------
// K1 (MFMA): h = x @ W1 bf16, plus as_[n]=h.att_src, ad_[n]=h.att_dst.
// 64 rows/block, 4 waves; wave -> 16 rows (1 M-tile) x 4 N-tiles, K=160 (5 steps).
// A staged fp32 LDS stride 164 (bank-uniform), converted at frag load.
// ---------------------------------------------------------------------------
__global__ void __launch_bounds__(256) k1_mfma(
        const float* __restrict__ x, const bf16* __restrict__ Bt,
        const float* __restrict__ att_src, const float* __restrict__ att_dst,
        bf16* __restrict__ h, float* __restrict__ as_, float* __restrict__ ad_) {
    __shared__ __align__(16) float As[64 * 164];
    __shared__ __align__(16) bf16 Bs[64 * 168];
    const int tid = threadIdx.x;
    const int rowbase = blockIdx.x * 64;

    // stage Bs (21504 B)
    {
        const uint4* s = (const uint4*)Bt;
        uint4* d = (uint4*)Bs;
        for (int i = tid; i < 1344; i += 256) d[i] = s[i];
    }
    // zero As pad cols 151..163
    for (int i = tid; i < 64 * 13; i += 256) {
        int r = i / 13, c = 151 + (i - r * 13);
        As[r * 164 + c] = 0.f;
    }
    // stage As: 64*151 = 9664 floats, coalesced flat float4, scatter to stride 164
    {
        const float4* xg = (const float4*)(x + (size_t)rowbase * 151);
        for (int i4 = tid; i4 < 2416; i4 += 256) {
            float4 v = xg[i4];
            float vals[4] = {v.x, v.y, v.z, v.w};
            int li = i4 * 4;
#pragma unroll
            for (int e = 0; e < 4; e++) {
                int idx = li + e;
                int r = idx / 151;
                int c = idx - r * 151;
                As[r * 164 + c] = vals[e];
            }
        }
    }
    __syncthreads();

    const int wv = tid >> 6, lane = tid & 63;
    const int quad = lane >> 4, m = lane & 15;

    f32x4 acc[4];
#pragma unroll
    for (int t = 0; t < 4; t++) acc[t] = (f32x4){0.f, 0.f, 0.f, 0.f};

    const float* Arow = &As[(wv * 16 + m) * 164];
#pragma unroll
    for (int ks = 0; ks < 5; ks++) {
        const int k0 = ks * 32 + quad * 8;
        float4 a0 = *(const float4*)&Arow[k0];
        float4 a1 = *(const float4*)&Arow[k0 + 4];
        bf16x8v af = {bfb(a0.x), bfb(a0.y), bfb(a0.z), bfb(a0.w),
                      bfb(a1.x), bfb(a1.y), bfb(a1.z), bfb(a1.w)};
#pragma unroll
        for (int t = 0; t < 4; t++) {
            bf16x8v bfr = *(const bf16x8v*)&Bs[(t * 16 + m) * 168 + k0];
            acc[t] = __builtin_amdgcn_mfma_f32_16x16x32_bf16(af, bfr, acc[t], 0, 0, 0);
        }
    }

    // epilogue: as_/ad_ per row + h writeback (packed bf16x2 via lane pairing)
    float as4[4], ad4[4];
#pragma unroll
    for (int t = 0; t < 4; t++) {
        as4[t] = att_src[t * 16 + m];
        ad4[t] = att_dst[t * 16 + m];
    }
#pragma unroll
    for (int r = 0; r < 3 + 1; r++) {
        float s = acc[0][r] * as4[0] + acc[1][r] * as4[1] +
                  acc[2][r] * as4[2] + acc[3][r] * as4[3];
        float d = acc[0][r] * ad4[0] + acc[1][r] * ad4[1] +
                  acc[2][r] * ad4[2] + acc[3][r] * ad4[3];
#pragma unroll
        for (int off = 1; off <= 8; off <<= 1) {
            s += __shfl_xor(s, off);
            d += __shfl_xor(d, off);
        }
        const int node = rowbase + wv * 16 + quad * 4 + r;
        if (m == 0) { as_[node] = s; ad_[node] = d; }
#pragma unroll
        for (int t = 0; t < 4; t++) {
            float val = acc[t][r];
            float oth = __shfl_xor(val, 1);
            if (!(lane & 1)) {
                unsigned int u = ((unsigned int)(unsigned short)bfb(oth) << 16) |
                                 (unsigned int)(unsigned short)bfb(val);
                *(unsigned int*)&h[(size_t)node * 64 + t * 16 + m] = u;
            }
        }
    }
}

// ---------------------------------------------------------------------------
// K2: per-edge: ex = exp(leakyrelu(as[src] + ad[dst])); AT[g][src_l][dst_l] += ex
// ---------------------------------------------------------------------------
__global__ void __launch_bounds__(256) k2_edges(
        const int* __restrict__ ei, const float* __restrict__ as_,
        const float* __restrict__ ad_, float* __restrict__ AT) {
    int e = blockIdx.x * 256 + threadIdx.x;
    if (e >= NEDGES_) return;
    int s = ei[e];
    int d = ei[NEDGES_ + e];
    float a = as_[s] + ad_[d];
    a = (a > 0.f) ? a : 0.2f * a;
    float ex = __expf(a);
    int g = s >> 7;
    atomicAdd(&AT[((size_t)g << 14) + ((size_t)(s & 127) << 7) + (d & 127)], ex);
}

// ---------------------------------------------------------------------------
// K3: one graph per block (see round-0 notes).
// ---------------------------------------------------------------------------
__global__ void __launch_bounds__(256) k3_graph(
        const float* __restrict__ ATg, const bf16* __restrict__ h,
        const float* __restrict__ as_, const float* __restrict__ ad_,
        const float* __restrict__ b1, const float* __restrict__ Wlin,
        const float* __restrict__ blin, float* __restrict__ out) {
    __shared__ __align__(16) bf16 At[128 * 128];
    __shared__ __align__(16) float hs[128 * 64];
    const int tid = threadIdx.x;
    const int g = blockIdx.x;
    const float* Ag = ATg + ((size_t)g << 14);
    const bf16* hg = h + ((size_t)g << 13);

    for (int i4 = tid; i4 < 4096; i4 += 256) {
        float4 v = ((const float4*)Ag)[i4];
        __hip_bfloat162* d2 = (__hip_bfloat162*)(At + i4 * 4);
        d2[0] = f2bf2(v.x, v.y);
        d2[1] = f2bf2(v.z, v.w);
    }
    __syncthreads();

    if (tid < 128) {
        int node = (g << 7) + tid;
        float a = as_[node] + ad_[node];
        a = (a > 0.f) ? a : 0.2f * a;
        float ex = __expf(a);
        At[tid * 128 + tid] =
            __float2bfloat16(__bfloat162float(At[tid * 128 + tid]) + ex);
    }
    __syncthreads();

    const int ic = tid & 127, jh = tid >> 7;
    {
        float p = 0.f;
        for (int j = jh * 64; j < jh * 64 + 64; j++)
            p += __bfloat162float(At[j * 128 + ic]);
        hs[tid] = p;
    }
    __syncthreads();
    {
        float inv = 1.f / (hs[ic] + hs[ic + 128]);
        for (int j = jh * 64; j < jh * 64 + 64; j++) {
            int ai = j * 128 + ic;
            At[ai] = __float2bfloat16(__bfloat162float(At[ai]) * inv);
        }
    }
    __syncthreads();

    for (int idx = tid; idx < 4096; idx += 256) {
        __hip_bfloat162 hv = ((const __hip_bfloat162*)hg)[idx];
        float2 f2 = __bfloat1622float2(hv);
        *(float2*)&hs[idx * 2] = f2;
    }
    __syncthreads();

    const int wv = tid >> 6, lane = tid & 63;
    const int i = ((wv & 1) << 6) | lane;
    const int f0 = (wv >> 1) << 5;
    float acc[32];
#pragma unroll
    for (int q = 0; q < 32; q++) acc[q] = 0.f;

    for (int j = 0; j < 128; j++) {
        float a = __bfloat162float(At[j * 128 + i]);
        const float4* hp = (const float4*)&hs[(j << 6) + f0];
#pragma unroll
        for (int q = 0; q < 8; q++) {
            float4 hv = hp[q];
            acc[4 * q + 0] += a * hv.x;
            acc[4 * q + 1] += a * hv.y;
            acc[4 * q + 2] += a * hv.z;
            acc[4 * q + 3] += a * hv.w;
        }
    }

    float p = 0.f;
    const float* wl = Wlin + i * 64 + f0;
#pragma unroll
    for (int q = 0; q < 8; q++) {
        float4 b4 = *(const float4*)&b1[f0 + 4 * q];
        float4 w4 = *(const float4*)&wl[4 * q];
        float o0 = acc[4 * q + 0] + b4.x; o0 = o0 > 0.f ? o0 : 0.f;
        float o1 = acc[4 * q + 1] + b4.y; o1 = o1 > 0.f ? o1 : 0.f;
        float o2 = acc[4 * q + 2] + b4.z; o2 = o2 > 0.f ? o2 : 0.f;
        float o3 = acc[4 * q + 3] + b4.w; o3 = o3 > 0.f ? o3 : 0.f;
        p += o0 * w4.x + o1 * w4.y + o2 * w4.z + o3 * w4.w;
    }
#pragma unroll
    for (int off = 32; off; off >>= 1) p += __shfl_xor(p, off);

    __syncthreads();
    if (lane == 0) ((float*)At)[wv] = p;
    __syncthreads();
    if (tid == 0) {
        float logit = ((float*)At)[0] + ((float*)At)[1] + ((float*)At)[2] +
                      ((float*)At)[3] + blin[0];
        out[g] = 1.f / (1.f + __expf(-logit));
    }
}

// ---------------------------------------------------------------------------
extern "C" void kernel_launch(void* const* d_in, const int* in_sizes, int n_in,
                              void* d_out, int out_size, void* d_ws, size_t ws_size,
                              hipStream_t stream) {
    (void)in_sizes; (void)n_in; (void)out_size; (void)ws_size;
    const float* x       = (const float*)d_in[0];
    const int*   ei      = (const int*)d_in[1];
    const float* W1      = (const float*)d_in[2];
    const float* att_src = (const float*)d_in[3];
    const float* att_dst = (const float*)d_in[4];
    const float* b1      = (const float*)d_in[5];
    const float* Wlin    = (const float*)d_in[6];
    const float* blin    = (const float*)d_in[7];
    float* out = (float*)d_out;

    char* ws = (char*)d_ws;
    bf16*  h   = (bf16*)ws;                          // 33,554,432 B
    float* as_ = (float*)(ws + 33554432);            // 1 MB
    float* ad_ = (float*)(ws + 34603008);            // 1 MB
    float* AT  = (float*)(ws + 35651584);            // 134,217,728 B
    bf16*  Bt  = (bf16*)(ws + 35651584 + 134217728); // 21,504 B

    (void)hipMemsetAsync(AT, 0, (size_t)G_ * NPG_ * NPG_ * sizeof(float), stream);
    k0_prep<<<42, 256, 0, stream>>>(W1, Bt);
    k1_mfma<<<NNODES_ / 64, 256, 0, stream>>>(x, Bt, att_src, att_dst, h, as_, ad_);
    k2_edges<<<NEDGES_ / 256, 256, 0, stream>>>(ei, as_, ad_, AT);
    k3_graph<<<G_, 256, 0, stream>>>(AT, h, as_, ad_, b1, Wlin, blin, out);
}